// Round 4
// baseline (421.983 us; speedup 1.0000x reference)
//
#include <hip/hip_runtime.h>
#include <math.h>

#define NT 16384
#define HID 2048
#define NE 256
#define NG 8
#define TOPG 4
#define TOPKK 8

constexpr int BM = 64;   // tokens per block
constexpr int KC = 32;   // K chunk

// ---------------------------------------------------------------------------
// Kernel A: scores = sigmoid(x @ W^T + bias), stored as f64 [NT][NE] in ws.
// fp32 products, per-chunk fp32 accumulate (1024 FMA/chunk), f64 chunk acc.
// 512 threads: tx = expert-col group (0..31), ty = token-row group (0..15).
// Per-thread output tile: 4 rows x 8 cols.
// ---------------------------------------------------------------------------
__global__ __launch_bounds__(512) void score_kernel(
    const float* __restrict__ x, const float* __restrict__ w,
    const float* __restrict__ bias, double* __restrict__ sd)
{
    __shared__ float xs[KC][BM];    // 8 KB, transposed: xs[k][token]
    __shared__ float wsm[KC][NE];   // 32 KB, transposed: wsm[k][expert]

    const int tid = threadIdx.x;
    const int tx = tid & 31;        // expert-column group
    const int ty = tid >> 5;        // token-row group (0..15), 4 rows each
    const int m0 = blockIdx.x * BM;

    // staging roles
    const int xrow = tid & 63;          // token row 0..63
    const int xko  = (tid >> 6) * 4;    // k-quad start 0,4,...,28
    const int wexp = tid & 255;         // expert 0..255
    const int wko  = (tid >> 8) * 16;   // k-half start 0 or 16

    double accd[4][8];
#pragma unroll
    for (int mi = 0; mi < 4; mi++)
#pragma unroll
        for (int j = 0; j < 8; j++) accd[mi][j] = 0.0;

    const float* wbase = w + (size_t)wexp * HID + wko;
    const float* xbase = x + (size_t)(m0 + xrow) * HID + xko;

    for (int k0 = 0; k0 < HID; k0 += KC) {
        // global loads first (hide latency)
        float4 wv0 = *(const float4*)(wbase + k0 + 0);
        float4 wv1 = *(const float4*)(wbase + k0 + 4);
        float4 wv2 = *(const float4*)(wbase + k0 + 8);
        float4 wv3 = *(const float4*)(wbase + k0 + 12);
        float4 xv  = *(const float4*)(xbase + k0);

        __syncthreads();   // previous iteration's LDS reads done

        // stage W transposed: wsm[k][expert]; bank = wexp%32 -> 2-way (free)
        wsm[wko +  0][wexp] = wv0.x; wsm[wko +  1][wexp] = wv0.y;
        wsm[wko +  2][wexp] = wv0.z; wsm[wko +  3][wexp] = wv0.w;
        wsm[wko +  4][wexp] = wv1.x; wsm[wko +  5][wexp] = wv1.y;
        wsm[wko +  6][wexp] = wv1.z; wsm[wko +  7][wexp] = wv1.w;
        wsm[wko +  8][wexp] = wv2.x; wsm[wko +  9][wexp] = wv2.y;
        wsm[wko + 10][wexp] = wv2.z; wsm[wko + 11][wexp] = wv2.w;
        wsm[wko + 12][wexp] = wv3.x; wsm[wko + 13][wexp] = wv3.y;
        wsm[wko + 14][wexp] = wv3.z; wsm[wko + 15][wexp] = wv3.w;
        xs[xko + 0][xrow] = xv.x;
        xs[xko + 1][xrow] = xv.y;
        xs[xko + 2][xrow] = xv.z;
        xs[xko + 3][xrow] = xv.w;

        __syncthreads();

        float accf[4][8];

        // peeled kk = 0: multiply (replaces zero-init + fma)
        {
            float4 a  = *(const float4*)&xs[0][ty * 4];
            float4 b0 = *(const float4*)&wsm[0][tx * 4];
            float4 b1 = *(const float4*)&wsm[0][128 + tx * 4];
            float av[4] = {a.x, a.y, a.z, a.w};
            float bv[8] = {b0.x, b0.y, b0.z, b0.w, b1.x, b1.y, b1.z, b1.w};
#pragma unroll
            for (int mi = 0; mi < 4; mi++)
#pragma unroll
                for (int j = 0; j < 8; j++)
                    accf[mi][j] = av[mi] * bv[j];
        }

#pragma unroll
        for (int kk = 1; kk < KC; kk++) {
            float4 a  = *(const float4*)&xs[kk][ty * 4];          // broadcast
            float4 b0 = *(const float4*)&wsm[kk][tx * 4];         // 2-way (free)
            float4 b1 = *(const float4*)&wsm[kk][128 + tx * 4];
            float av[4] = {a.x, a.y, a.z, a.w};
            float bv[8] = {b0.x, b0.y, b0.z, b0.w, b1.x, b1.y, b1.z, b1.w};
#pragma unroll
            for (int mi = 0; mi < 4; mi++)
#pragma unroll
                for (int j = 0; j < 8; j++)
                    accf[mi][j] = fmaf(av[mi], bv[j], accf[mi][j]);
        }

#pragma unroll
        for (int mi = 0; mi < 4; mi++)
#pragma unroll
            for (int j = 0; j < 8; j++) accd[mi][j] += (double)accf[mi][j];
    }

    // epilogue: add bias, sigmoid in f64, store
#pragma unroll
    for (int mi = 0; mi < 4; mi++) {
        const size_t row = (size_t)(m0 + ty * 4 + mi) * NE;
#pragma unroll
        for (int j = 0; j < 8; j++) {
            const int n = (j < 4) ? (tx * 4 + j) : (128 + tx * 4 + (j - 4));
            double z = accd[mi][j] + (double)bias[n];
            double s = 1.0 / (1.0 + exp(-z));
            sd[row + n] = s;
        }
    }
}

// ---------------------------------------------------------------------------
// Kernel B: grouped routing. One wave (64 lanes) per token; lane l owns
// experts [4l, 4l+3]; group g = experts [32g, 32g+31] = lanes [8g, 8g+7].
// (unchanged — proven correct in round 2)
// ---------------------------------------------------------------------------
__global__ __launch_bounds__(256) void route_kernel(
    const double* __restrict__ sd, const float* __restrict__ bias,
    float* __restrict__ wout, float* __restrict__ iout)
{
    const int lane = threadIdx.x & 63;
    const int wid  = threadIdx.x >> 6;
    const int tok  = blockIdx.x * 4 + wid;
    const double* srow = sd + (size_t)tok * NE;
    const int e0 = lane * 4;

    const double NEG = -__builtin_inf();

    double s0 = srow[e0 + 0], s1 = srow[e0 + 1], s2 = srow[e0 + 2], s3 = srow[e0 + 3];
    double sb0 = s0 + (double)bias[e0 + 0];
    double sb1 = s1 + (double)bias[e0 + 1];
    double sb2 = s2 + (double)bias[e0 + 2];
    double sb3 = s3 + (double)bias[e0 + 3];

    // per-lane top-2 of 4
    double m1 = sb0, m2 = NEG;
    if (sb1 > m1) { m2 = m1; m1 = sb1; } else if (sb1 > m2) m2 = sb1;
    if (sb2 > m1) { m2 = m1; m1 = sb2; } else if (sb2 > m2) m2 = sb2;
    if (sb3 > m1) { m2 = m1; m1 = sb3; } else if (sb3 > m2) m2 = sb3;

    // 8-lane butterfly merge of top-2 pairs (within group)
#pragma unroll
    for (int mask = 1; mask <= 4; mask <<= 1) {
        double o1 = __shfl_xor(m1, mask);
        double o2 = __shfl_xor(m2, mask);
        double n1 = fmax(m1, o1);
        double n2 = fmax(fmin(m1, o1), fmax(m2, o2));
        m1 = n1; m2 = n2;
    }
    double gs = m1 + m2;   // group score

    double g[8];
#pragma unroll
    for (int j = 0; j < 8; j++) g[j] = __shfl(gs, j * 8);

    const int myg = lane >> 3;
    int rank = 0;
#pragma unroll
    for (int j = 0; j < 8; j++)
        rank += (g[j] > g[myg] || (g[j] == g[myg] && j < myg)) ? 1 : 0;
    const bool keep = (rank < TOPG);

    double v0 = keep ? sb0 : NEG;
    double v1 = keep ? sb1 : NEG;
    double v2 = keep ? sb2 : NEG;
    double v3 = keep ? sb3 : NEG;

    double wv[TOPKK];
    int    idx[TOPKK];

#pragma unroll
    for (int r = 0; r < TOPKK; r++) {
        double bvv = v0; int bi = e0;
        if (v1 > bvv) { bvv = v1; bi = e0 + 1; }
        if (v2 > bvv) { bvv = v2; bi = e0 + 2; }
        if (v3 > bvv) { bvv = v3; bi = e0 + 3; }
#pragma unroll
        for (int mask = 1; mask <= 32; mask <<= 1) {
            double ov = __shfl_xor(bvv, mask);
            int    oi = __shfl_xor(bi, mask);
            if (ov > bvv || (ov == bvv && oi < bi)) { bvv = ov; bi = oi; }
        }
        const int sel   = bi & 3;
        const int owner = bi >> 2;
        double cands = (sel == 0) ? s0 : (sel == 1) ? s1 : (sel == 2) ? s2 : s3;
        wv[r]  = __shfl(cands, owner);
        idx[r] = bi;
        if (lane == owner) {
            if (sel == 0) v0 = NEG;
            else if (sel == 1) v1 = NEG;
            else if (sel == 2) v2 = NEG;
            else v3 = NEG;
        }
    }

    double sum = 0.0;
#pragma unroll
    for (int r = 0; r < TOPKK; r++) sum += wv[r];
    const double scale = 2.5 / sum;

    if (lane == 0) {
#pragma unroll
        for (int r = 0; r < TOPKK; r++)
            wout[(size_t)tok * TOPKK + r] = (float)(wv[r] * scale);
#pragma unroll
        for (int r = 0; r < TOPKK; r++)
            iout[(size_t)tok * TOPKK + r] = (float)idx[r];
    }
}

// ---------------------------------------------------------------------------
extern "C" void kernel_launch(void* const* d_in, const int* in_sizes, int n_in,
                              void* d_out, int out_size, void* d_ws, size_t ws_size,
                              hipStream_t stream) {
    const float* x = (const float*)d_in[0];
    const float* w = (const float*)d_in[1];
    const float* b = (const float*)d_in[2];

    double* sd = (double*)d_ws;                 // [NT][NE] f64 sigmoid scores (32 MB)
    float* wout = (float*)d_out;                // [NT][8] weights
    float* iout = wout + (size_t)NT * TOPKK;    // [NT][8] indices stored as float

    score_kernel<<<NT / BM, 512, 0, stream>>>(x, w, b, sd);
    route_kernel<<<NT / 4, 256, 0, stream>>>(sd, b, wout, iout);
}